// Round 1
// baseline (2186.159 us; speedup 1.0000x reference)
//
#include <hip/hip_runtime.h>

#define D 128
#define ROWS_PER_BLOCK 64

__device__ __forceinline__ void atomicMaxFloat(float* addr, float val) {
    // Standard int-punned float max. Init value must be 0xFFFFFFFF (-NaN):
    // as int it is -1 (below all non-negative float bit patterns), as
    // unsigned it is max (above all negative float bit patterns).
    if (val >= 0.0f) atomicMax((int*)addr, __float_as_int(val));
    else             atomicMin((unsigned int*)addr, __float_as_uint(val));
}

// ---------------- kernel 1: gate = x @ Wg + bg; segmax = segment_max(gate) ---
__global__ __launch_bounds__(256) void k_gate(
        const float* __restrict__ x, const int* __restrict__ index,
        const float* __restrict__ Wg, const float* __restrict__ bg,
        float* __restrict__ gate, float* __restrict__ segmax, int nrows) {
    int tid  = blockIdx.x * blockDim.x + threadIdx.x;
    int row  = tid >> 5;        // 32 lanes per row
    int lane = tid & 31;
    if (row >= nrows) return;
    const float4 xv = *(const float4*)(x + (size_t)row * D + lane * 4);
    const float4 wv = *(const float4*)(Wg + lane * 4);
    float s = xv.x * wv.x + xv.y * wv.y + xv.z * wv.z + xv.w * wv.w;
    // reduce across the 32-lane group (xor<=16 stays within the group)
    #pragma unroll
    for (int off = 16; off >= 1; off >>= 1) s += __shfl_xor(s, off, 64);
    if (lane == 0) {
        float g = s + bg[0];
        gate[row] = g;
        atomicMaxFloat(&segmax[index[row]], g);
    }
}

// ---------------- kernel 2: e = exp(gate - segmax[idx]); segsum += e ---------
__global__ __launch_bounds__(256) void k_exp(
        const int* __restrict__ index, const float* __restrict__ segmax,
        float* __restrict__ gate, float* __restrict__ segsum, int n) {
    int i = blockIdx.x * blockDim.x + threadIdx.x;
    if (i >= n) return;
    int s = index[i];
    float e = __expf(gate[i] - segmax[s]);
    gate[i] = e;                        // overwrite gate with e
    atomicAdd(&segsum[s], e);
}

// ---------------- kernel 3: pooled[idx] += (e/(segsum+1e-10)) * x ------------
__global__ __launch_bounds__(256) void k_pool(
        const float* __restrict__ x, const int* __restrict__ index,
        const float* __restrict__ e, const float* __restrict__ segsum,
        float* __restrict__ pooled, int nrows) {
    int tid  = blockIdx.x * blockDim.x + threadIdx.x;
    int row  = tid >> 5;
    int lane = tid & 31;
    if (row >= nrows) return;
    int s = index[row];
    float w = e[row] / (segsum[s] + 1e-10f);
    const float4 xv = *(const float4*)(x + (size_t)row * D + lane * 4);
    float* p = pooled + (size_t)s * D + lane * 4;
    atomicAdd(p + 0, w * xv.x);
    atomicAdd(p + 1, w * xv.y);
    atomicAdd(p + 2, w * xv.z);
    atomicAdd(p + 3, w * xv.w);
}

// ---------------- kernel 4: out = pooled @ Wm + (segsum/(segsum+1e-10))*bm ---
__global__ __launch_bounds__(256) void k_out(
        const float* __restrict__ pooled, const float* __restrict__ Wm,
        const float* __restrict__ bm, const float* __restrict__ segsum,
        float* __restrict__ out, int S) {
    __shared__ float wlds[D * D];       // 64 KiB: whole Wm
    for (int i = threadIdx.x * 4; i < D * D; i += blockDim.x * 4)
        *(float4*)(wlds + i) = *(const float4*)(Wm + i);
    __syncthreads();
    const int c4   = (threadIdx.x & 31) * 4;   // 4 output columns per thread
    const int rsub = threadIdx.x >> 5;         // 8 rows in flight per block
    const int rowEnd = min((blockIdx.x + 1) * ROWS_PER_BLOCK, S);
    for (int r = blockIdx.x * ROWS_PER_BLOCK + rsub; r < rowEnd; r += 8) {
        const float* pr = pooled + (size_t)r * D;
        float ax = 0.f, ay = 0.f, az = 0.f, aw = 0.f;
        #pragma unroll
        for (int k = 0; k < D; k += 4) {
            float4 pv = *(const float4*)(pr + k);
            float4 w0 = *(const float4*)(wlds + (k + 0) * D + c4);
            float4 w1 = *(const float4*)(wlds + (k + 1) * D + c4);
            float4 w2 = *(const float4*)(wlds + (k + 2) * D + c4);
            float4 w3 = *(const float4*)(wlds + (k + 3) * D + c4);
            ax += pv.x * w0.x + pv.y * w1.x + pv.z * w2.x + pv.w * w3.x;
            ay += pv.x * w0.y + pv.y * w1.y + pv.z * w2.y + pv.w * w3.y;
            az += pv.x * w0.z + pv.y * w1.z + pv.z * w2.z + pv.w * w3.z;
            aw += pv.x * w0.w + pv.y * w1.w + pv.z * w2.w + pv.w * w3.w;
        }
        float ssv = segsum[r];
        float wsc = ssv / (ssv + 1e-10f);       // = sum of softmax weights
        float4 bv = *(const float4*)(bm + c4);
        float4 o;
        o.x = ax + wsc * bv.x; o.y = ay + wsc * bv.y;
        o.z = az + wsc * bv.z; o.w = aw + wsc * bv.w;
        *(float4*)(out + (size_t)r * D + c4) = o;
    }
}

extern "C" void kernel_launch(void* const* d_in, const int* in_sizes, int n_in,
                              void* d_out, int out_size, void* d_ws, size_t ws_size,
                              hipStream_t stream) {
    const float* x     = (const float*)d_in[0];
    const int*   index = (const int*)  d_in[1];
    const float* Wg    = (const float*)d_in[2];
    const float* bg    = (const float*)d_in[3];
    const float* Wm    = (const float*)d_in[4];
    const float* bm    = (const float*)d_in[5];
    float* out = (float*)d_out;

    const int N_ = in_sizes[0] / D;     // 1,000,000
    const int S_ = out_size / D;        // 50,000

    // workspace layout (floats): [segmax S][segsum S][pooled S*D][gate N]
    float* ws_f   = (float*)d_ws;
    float* segmax = ws_f;
    float* segsum = ws_f + S_;
    float* pooled = ws_f + 2 * (size_t)S_;                 // byte off 400000, 16B aligned
    float* gate   = pooled + (size_t)S_ * D;

    // init: segmax = -NaN (0xFF bytes), segsum+pooled = 0 (contiguous)
    hipMemsetAsync(segmax, 0xFF, (size_t)S_ * sizeof(float), stream);
    hipMemsetAsync(segsum, 0, ((size_t)S_ + (size_t)S_ * D) * sizeof(float), stream);

    dim3 blk(256);
    k_gate<<<dim3((N_ * 32 + 255) / 256), blk, 0, stream>>>(x, index, Wg, bg, gate, segmax, N_);
    k_exp <<<dim3((N_ + 255) / 256),       blk, 0, stream>>>(index, segmax, gate, segsum, N_);
    k_pool<<<dim3((N_ * 32 + 255) / 256), blk, 0, stream>>>(x, index, gate, segsum, pooled, N_);
    k_out <<<dim3((S_ + ROWS_PER_BLOCK - 1) / ROWS_PER_BLOCK), blk, 0, stream>>>(pooled, Wm, bm, segsum, out, S_);
}

// Round 2
// 890.860 us; speedup vs baseline: 2.4540x; 2.4540x over previous
//
#include <hip/hip_runtime.h>

#define D 128

// ---------------- kernel 1: histogram of segment ids -------------------------
__global__ __launch_bounds__(256) void k_hist(
        const int* __restrict__ index, int* __restrict__ cnt, int n) {
    int i = blockIdx.x * blockDim.x + threadIdx.x;
    if (i < n) atomicAdd(&cnt[index[i]], 1);
}

// ---------------- kernel 2: exclusive scan cnt -> cursor (single block) ------
__global__ __launch_bounds__(256) void k_scan(
        const int* __restrict__ cnt, int* __restrict__ cursor, int S) {
    __shared__ int buf[256];
    __shared__ int carry;
    if (threadIdx.x == 0) carry = 0;
    __syncthreads();
    for (int base = 0; base < S; base += 256) {
        int i = base + threadIdx.x;
        int v = (i < S) ? cnt[i] : 0;
        buf[threadIdx.x] = v;
        __syncthreads();
        #pragma unroll
        for (int off = 1; off < 256; off <<= 1) {
            int t = (threadIdx.x >= off) ? buf[threadIdx.x - off] : 0;
            __syncthreads();
            buf[threadIdx.x] += t;
            __syncthreads();
        }
        int incl = buf[threadIdx.x];
        if (i < S) cursor[i] = carry + incl - v;   // exclusive prefix
        __syncthreads();
        if (threadIdx.x == 255) carry += buf[255];
        __syncthreads();
    }
}

// ---------------- kernel 3: scatter row ids into segment-sorted perm ---------
__global__ __launch_bounds__(256) void k_scatter(
        const int* __restrict__ index, int* __restrict__ cursor,
        int* __restrict__ perm, int n) {
    int i = blockIdx.x * blockDim.x + threadIdx.x;
    if (i < n) {
        int pos = atomicAdd(&cursor[index[i]], 1);
        perm[pos] = i;
    }
}

// ---------------- kernel 4: fused gate + softmax + pooled (1 wave / segment) -
// After k_scatter, cursor[s] == end offset of segment s; start = end - cnt[s].
// Writes pooled[s] = (sum_e_x) / (sum_e + 1e-10) and sum_e (punned float)
// back over cursor[s] for k_out's bias scaling.
__global__ __launch_bounds__(256) void k_main(
        const float* __restrict__ x, const int* __restrict__ perm,
        const int* __restrict__ cnt, int* __restrict__ cursor,
        const float* __restrict__ Wg, const float* __restrict__ bg,
        float* __restrict__ pooled, int S) {
    int wid  = (blockIdx.x * blockDim.x + threadIdx.x) >> 6;   // wave id = segment
    int lane = threadIdx.x & 63;
    if (wid >= S) return;
    int n     = cnt[wid];
    int start = cursor[wid] - n;
    const float2 wv = *(const float2*)(Wg + lane * 2);
    const float b0 = bg[0];
    float ax = 0.f, ay = 0.f, se = 0.f;
    // manual 1-deep prefetch: next row's load issues before current reduce chain
    int rid = (n > 0) ? perm[start] : 0;
    float2 xv = (n > 0) ? *(const float2*)(x + (size_t)rid * D + lane * 2)
                        : make_float2(0.f, 0.f);
    for (int j = 0; j < n; ++j) {
        float2 cur = xv;
        if (j + 1 < n) {
            rid = perm[start + j + 1];
            xv  = *(const float2*)(x + (size_t)rid * D + lane * 2);
        }
        float p = cur.x * wv.x + cur.y * wv.y;
        #pragma unroll
        for (int off = 32; off >= 1; off >>= 1) p += __shfl_xor(p, off, 64);
        float e = __expf(p + b0);           // no max-subtract: cancels in ratio
        ax += e * cur.x; ay += e * cur.y; se += e;
    }
    float inv = 1.f / (se + 1e-10f);
    *(float2*)(pooled + (size_t)wid * D + lane * 2) = make_float2(ax * inv, ay * inv);
    if (lane == 0) ((float*)cursor)[wid] = se;   // segsum for k_out
}

// ---------------- kernel 5: out = pooled @ Wm + (se/(se+1e-10))*bm -----------
#define ROWS_PER_BLOCK 64
__global__ __launch_bounds__(256) void k_out(
        const float* __restrict__ pooled, const float* __restrict__ Wm,
        const float* __restrict__ bm, const float* __restrict__ segsum,
        float* __restrict__ out, int S) {
    __shared__ float wlds[D * D];       // 64 KiB: whole Wm
    for (int i = threadIdx.x * 4; i < D * D; i += blockDim.x * 4)
        *(float4*)(wlds + i) = *(const float4*)(Wm + i);
    __syncthreads();
    const int c4   = (threadIdx.x & 31) * 4;
    const int rsub = threadIdx.x >> 5;
    const int rowEnd = min((blockIdx.x + 1) * ROWS_PER_BLOCK, S);
    for (int r = blockIdx.x * ROWS_PER_BLOCK + rsub; r < rowEnd; r += 8) {
        const float* pr = pooled + (size_t)r * D;
        float ax = 0.f, ay = 0.f, az = 0.f, aw = 0.f;
        #pragma unroll
        for (int k = 0; k < D; k += 4) {
            float4 pv = *(const float4*)(pr + k);
            float4 w0 = *(const float4*)(wlds + (k + 0) * D + c4);
            float4 w1 = *(const float4*)(wlds + (k + 1) * D + c4);
            float4 w2 = *(const float4*)(wlds + (k + 2) * D + c4);
            float4 w3 = *(const float4*)(wlds + (k + 3) * D + c4);
            ax += pv.x * w0.x + pv.y * w1.x + pv.z * w2.x + pv.w * w3.x;
            ay += pv.x * w0.y + pv.y * w1.y + pv.z * w2.y + pv.w * w3.y;
            az += pv.x * w0.z + pv.y * w1.z + pv.z * w2.z + pv.w * w3.z;
            aw += pv.x * w0.w + pv.y * w1.w + pv.z * w2.w + pv.w * w3.w;
        }
        float ssv = segsum[r];
        float wsc = ssv / (ssv + 1e-10f);
        float4 bv = *(const float4*)(bm + c4);
        float4 o;
        o.x = ax + wsc * bv.x; o.y = ay + wsc * bv.y;
        o.z = az + wsc * bv.z; o.w = aw + wsc * bv.w;
        *(float4*)(out + (size_t)r * D + c4) = o;
    }
}

extern "C" void kernel_launch(void* const* d_in, const int* in_sizes, int n_in,
                              void* d_out, int out_size, void* d_ws, size_t ws_size,
                              hipStream_t stream) {
    const float* x     = (const float*)d_in[0];
    const int*   index = (const int*)  d_in[1];
    const float* Wg    = (const float*)d_in[2];
    const float* bg    = (const float*)d_in[3];
    const float* Wm    = (const float*)d_in[4];
    const float* bm    = (const float*)d_in[5];
    float* out = (float*)d_out;

    const int N_ = in_sizes[0] / D;     // 1,000,000
    const int S_ = out_size / D;        // 50,000

    // workspace (30.0 MB): [cnt S int][cursor S int][perm N int][pooled S*D f32]
    int*   cnt    = (int*)d_ws;
    int*   cursor = cnt + S_;
    int*   perm   = cursor + S_;
    float* pooled = (float*)(perm + (size_t)N_);

    hipMemsetAsync(cnt, 0, (size_t)S_ * sizeof(int), stream);

    dim3 blk(256);
    k_hist   <<<dim3((N_ + 255) / 256), blk, 0, stream>>>(index, cnt, N_);
    k_scan   <<<dim3(1),                blk, 0, stream>>>(cnt, cursor, S_);
    k_scatter<<<dim3((N_ + 255) / 256), blk, 0, stream>>>(index, cursor, perm, N_);
    k_main   <<<dim3((S_ + 3) / 4),     blk, 0, stream>>>(x, perm, cnt, cursor, Wg, bg, pooled, S_);
    k_out    <<<dim3((S_ + ROWS_PER_BLOCK - 1) / ROWS_PER_BLOCK), blk, 0, stream>>>(
                 pooled, Wm, bm, (const float*)cursor, out, S_);
}

// Round 3
// 367.785 us; speedup vs baseline: 5.9441x; 2.4222x over previous
//
#include <hip/hip_runtime.h>

#define D 128

// ---------------- kernel 1: histogram of segment ids -------------------------
__global__ __launch_bounds__(256) void k_hist(
        const int* __restrict__ index, int* __restrict__ cnt, int n) {
    int i = blockIdx.x * blockDim.x + threadIdx.x;
    if (i < n) atomicAdd(&cnt[index[i]], 1);
}

// ---------------- hierarchical exclusive scan: cnt -> cursor -----------------
// A: each block scans a 2048-chunk (256 thr x 8), writes exclusive prefixes
//    into cursor and its chunk total into bsum[blockIdx].
#define SCAN_CHUNK 2048
__global__ __launch_bounds__(256) void k_scanA(
        const int* __restrict__ cnt, int* __restrict__ cursor,
        int* __restrict__ bsum, int S) {
    __shared__ int tsum[256];
    const int base = blockIdx.x * SCAN_CHUNK;
    int vals[8]; int local = 0;
    #pragma unroll
    for (int j = 0; j < 8; ++j) {
        int i = base + threadIdx.x * 8 + j;
        vals[j] = (i < S) ? cnt[i] : 0;
        local += vals[j];
    }
    tsum[threadIdx.x] = local;
    __syncthreads();
    #pragma unroll
    for (int off = 1; off < 256; off <<= 1) {
        int t = (threadIdx.x >= off) ? tsum[threadIdx.x - off] : 0;
        __syncthreads();
        tsum[threadIdx.x] += t;
        __syncthreads();
    }
    int excl = tsum[threadIdx.x] - local;
    #pragma unroll
    for (int j = 0; j < 8; ++j) {
        int i = base + threadIdx.x * 8 + j;
        if (i < S) cursor[i] = excl;
        excl += vals[j];
    }
    if (threadIdx.x == 255) bsum[blockIdx.x] = tsum[255];
}

// B: single block scans the (<=256) block sums to exclusive prefixes.
__global__ __launch_bounds__(256) void k_scanB(int* __restrict__ bsum, int nb) {
    __shared__ int buf[256];
    int v = (threadIdx.x < nb) ? bsum[threadIdx.x] : 0;
    buf[threadIdx.x] = v;
    __syncthreads();
    #pragma unroll
    for (int off = 1; off < 256; off <<= 1) {
        int t = (threadIdx.x >= off) ? buf[threadIdx.x - off] : 0;
        __syncthreads();
        buf[threadIdx.x] += t;
        __syncthreads();
    }
    if (threadIdx.x < nb) bsum[threadIdx.x] = buf[threadIdx.x] - v;
}

// C: add scanned block offsets back.
__global__ __launch_bounds__(256) void k_scanC(
        int* __restrict__ cursor, const int* __restrict__ bsum, int S) {
    int i = blockIdx.x * blockDim.x + threadIdx.x;
    if (i < S) cursor[i] += bsum[i / SCAN_CHUNK];
}

// ---------------- scatter row ids into segment-sorted perm -------------------
__global__ __launch_bounds__(256) void k_scatter(
        const int* __restrict__ index, int* __restrict__ cursor,
        int* __restrict__ perm, int n) {
    int i = blockIdx.x * blockDim.x + threadIdx.x;
    if (i < n) {
        int pos = atomicAdd(&cursor[index[i]], 1);
        perm[pos] = i;
    }
}

// ---------------- fused gate + softmax + pooled (1 wave / segment) -----------
// After k_scatter, cursor[s] == end offset of segment s; start = end - cnt[s].
// Writes pooled[s] = sum(e*x)/(sum_e+1e-10); stores sum_e (punned) in cursor[s].
__global__ __launch_bounds__(256) void k_main(
        const float* __restrict__ x, const int* __restrict__ perm,
        const int* __restrict__ cnt, int* __restrict__ cursor,
        const float* __restrict__ Wg, const float* __restrict__ bg,
        float* __restrict__ pooled, int S) {
    int wid  = (blockIdx.x * blockDim.x + threadIdx.x) >> 6;   // wave = segment
    int lane = threadIdx.x & 63;
    if (wid >= S) return;
    int n     = cnt[wid];
    int start = cursor[wid] - n;
    const float2 wv = *(const float2*)(Wg + lane * 2);
    const float b0 = bg[0];
    float ax = 0.f, ay = 0.f, se = 0.f;
    int rid = (n > 0) ? perm[start] : 0;
    float2 xv = (n > 0) ? *(const float2*)(x + (size_t)rid * D + lane * 2)
                        : make_float2(0.f, 0.f);
    for (int j = 0; j < n; ++j) {
        float2 cur = xv;
        if (j + 1 < n) {
            rid = perm[start + j + 1];
            xv  = *(const float2*)(x + (size_t)rid * D + lane * 2);
        }
        float p = cur.x * wv.x + cur.y * wv.y;
        #pragma unroll
        for (int off = 32; off >= 1; off >>= 1) p += __shfl_xor(p, off, 64);
        float e = __expf(p + b0);           // no max-subtract: cancels in ratio
        ax += e * cur.x; ay += e * cur.y; se += e;
    }
    float inv = 1.f / (se + 1e-10f);
    *(float2*)(pooled + (size_t)wid * D + lane * 2) = make_float2(ax * inv, ay * inv);
    if (lane == 0) ((float*)cursor)[wid] = se;   // segsum for k_out
}

// ---------------- out = pooled @ Wm + (se/(se+1e-10))*bm ---------------------
// Register-blocked tiled GEMM: C-tile 64x128, K-tile 16, thread = 8x4 micro.
#define OUT_ROWS 64
__global__ __launch_bounds__(256) void k_out(
        const float* __restrict__ pooled, const float* __restrict__ Wm,
        const float* __restrict__ bm, const float* __restrict__ segsum,
        float* __restrict__ out, int S) {
    __shared__ float Alds[16][64];       // [kk][row] 4 KiB
    __shared__ float Blds[16][128];      // [kk][col] 8 KiB
    const int tx = threadIdx.x & 31;     // col group: cols tx*4..tx*4+3
    const int ty = threadIdx.x >> 5;     // row group: rows ty*8..ty*8+7
    const int r0 = blockIdx.x * OUT_ROWS;
    float acc[8][4] = {{0.f}};
    const int arow = threadIdx.x & 63;   // staging role
    const int akq  = threadIdx.x >> 6;   // 0..3 -> k quad
    const int brow = threadIdx.x >> 4;   // 0..15 -> kk   (t*8/128)
    const int bcol = (threadIdx.x & 15) * 8;

    for (int k0 = 0; k0 < D; k0 += 16) {
        // stage A (transposed) : Alds[kk][row] = pooled[r0+row][k0+kk]
        float4 av = make_float4(0.f, 0.f, 0.f, 0.f);
        if (r0 + arow < S)
            av = *(const float4*)(pooled + (size_t)(r0 + arow) * D + k0 + akq * 4);
        Alds[akq * 4 + 0][arow] = av.x;
        Alds[akq * 4 + 1][arow] = av.y;
        Alds[akq * 4 + 2][arow] = av.z;
        Alds[akq * 4 + 3][arow] = av.w;
        // stage B : Blds[kk][c] = Wm[k0+kk][c], 8 floats/thread
        *(float4*)(&Blds[brow][bcol])     = *(const float4*)(Wm + (size_t)(k0 + brow) * D + bcol);
        *(float4*)(&Blds[brow][bcol + 4]) = *(const float4*)(Wm + (size_t)(k0 + brow) * D + bcol + 4);
        __syncthreads();
        #pragma unroll
        for (int kk = 0; kk < 16; ++kk) {
            float4 a0 = *(const float4*)(&Alds[kk][ty * 8]);
            float4 a1 = *(const float4*)(&Alds[kk][ty * 8 + 4]);
            float4 b  = *(const float4*)(&Blds[kk][tx * 4]);
            float av8[8] = {a0.x, a0.y, a0.z, a0.w, a1.x, a1.y, a1.z, a1.w};
            #pragma unroll
            for (int i = 0; i < 8; ++i) {
                acc[i][0] += av8[i] * b.x;
                acc[i][1] += av8[i] * b.y;
                acc[i][2] += av8[i] * b.z;
                acc[i][3] += av8[i] * b.w;
            }
        }
        __syncthreads();
    }
    const float4 bv = *(const float4*)(bm + tx * 4);
    #pragma unroll
    for (int i = 0; i < 8; ++i) {
        int r = r0 + ty * 8 + i;
        if (r < S) {
            float ssv = segsum[r];
            float wsc = ssv / (ssv + 1e-10f);
            float4 o;
            o.x = acc[i][0] + wsc * bv.x;
            o.y = acc[i][1] + wsc * bv.y;
            o.z = acc[i][2] + wsc * bv.z;
            o.w = acc[i][3] + wsc * bv.w;
            *(float4*)(out + (size_t)r * D + tx * 4) = o;
        }
    }
}

extern "C" void kernel_launch(void* const* d_in, const int* in_sizes, int n_in,
                              void* d_out, int out_size, void* d_ws, size_t ws_size,
                              hipStream_t stream) {
    const float* x     = (const float*)d_in[0];
    const int*   index = (const int*)  d_in[1];
    const float* Wg    = (const float*)d_in[2];
    const float* bg    = (const float*)d_in[3];
    const float* Wm    = (const float*)d_in[4];
    const float* bm    = (const float*)d_in[5];
    float* out = (float*)d_out;

    const int N_ = in_sizes[0] / D;     // 1,000,000
    const int S_ = out_size / D;        // 50,000

    // workspace: [cnt S][cursor S][bsum 256][perm N][pooled S*D]
    int*   cnt    = (int*)d_ws;
    int*   cursor = cnt + S_;
    int*   bsum   = cursor + S_;
    int*   perm   = bsum + 256;
    float* pooled = (float*)(perm + (size_t)N_);

    const int nb = (S_ + SCAN_CHUNK - 1) / SCAN_CHUNK;    // 25

    hipMemsetAsync(cnt, 0, (size_t)S_ * sizeof(int), stream);

    dim3 blk(256);
    k_hist   <<<dim3((N_ + 255) / 256), blk, 0, stream>>>(index, cnt, N_);
    k_scanA  <<<dim3(nb),               blk, 0, stream>>>(cnt, cursor, bsum, S_);
    k_scanB  <<<dim3(1),                blk, 0, stream>>>(bsum, nb);
    k_scanC  <<<dim3((S_ + 255) / 256), blk, 0, stream>>>(cursor, bsum, S_);
    k_scatter<<<dim3((N_ + 255) / 256), blk, 0, stream>>>(index, cursor, perm, N_);
    k_main   <<<dim3((S_ + 3) / 4),     blk, 0, stream>>>(x, perm, cnt, cursor, Wg, bg, pooled, S_);
    k_out    <<<dim3((S_ + OUT_ROWS - 1) / OUT_ROWS), blk, 0, stream>>>(
                 pooled, Wm, bm, (const float*)cursor, out, S_);
}

// Round 4
// 292.711 us; speedup vs baseline: 7.4687x; 1.2565x over previous
//
#include <hip/hip_runtime.h>

#define D 128

// ---------------- kernel 1: histogram of segment ids -------------------------
__global__ __launch_bounds__(256) void k_hist(
        const int* __restrict__ index, int* __restrict__ cnt, int n) {
    int i = blockIdx.x * blockDim.x + threadIdx.x;
    if (i < n) atomicAdd(&cnt[index[i]], 1);
}

// ---------------- hierarchical exclusive scan: cnt -> cursor -----------------
#define SCAN_CHUNK 2048
__global__ __launch_bounds__(256) void k_scanA(
        const int* __restrict__ cnt, int* __restrict__ cursor,
        int* __restrict__ bsum, int S) {
    __shared__ int tsum[256];
    const int base = blockIdx.x * SCAN_CHUNK;
    int vals[8]; int local = 0;
    #pragma unroll
    for (int j = 0; j < 8; ++j) {
        int i = base + threadIdx.x * 8 + j;
        vals[j] = (i < S) ? cnt[i] : 0;
        local += vals[j];
    }
    tsum[threadIdx.x] = local;
    __syncthreads();
    #pragma unroll
    for (int off = 1; off < 256; off <<= 1) {
        int t = (threadIdx.x >= off) ? tsum[threadIdx.x - off] : 0;
        __syncthreads();
        tsum[threadIdx.x] += t;
        __syncthreads();
    }
    int excl = tsum[threadIdx.x] - local;
    #pragma unroll
    for (int j = 0; j < 8; ++j) {
        int i = base + threadIdx.x * 8 + j;
        if (i < S) cursor[i] = excl;
        excl += vals[j];
    }
    if (threadIdx.x == 255) bsum[blockIdx.x] = tsum[255];
}

__global__ __launch_bounds__(256) void k_scanB(int* __restrict__ bsum, int nb) {
    __shared__ int buf[256];
    int v = (threadIdx.x < nb) ? bsum[threadIdx.x] : 0;
    buf[threadIdx.x] = v;
    __syncthreads();
    #pragma unroll
    for (int off = 1; off < 256; off <<= 1) {
        int t = (threadIdx.x >= off) ? buf[threadIdx.x - off] : 0;
        __syncthreads();
        buf[threadIdx.x] += t;
        __syncthreads();
    }
    if (threadIdx.x < nb) bsum[threadIdx.x] = buf[threadIdx.x] - v;
}

__global__ __launch_bounds__(256) void k_scanC(
        int* __restrict__ cursor, const int* __restrict__ bsum, int S) {
    int i = blockIdx.x * blockDim.x + threadIdx.x;
    if (i < S) cursor[i] += bsum[i / SCAN_CHUNK];
}

// ---------------- scatter row ids into segment-sorted perm -------------------
__global__ __launch_bounds__(256) void k_scatter(
        const int* __restrict__ index, int* __restrict__ cursor,
        int* __restrict__ perm, int n) {
    int i = blockIdx.x * blockDim.x + threadIdx.x;
    if (i < n) {
        int pos = atomicAdd(&cursor[index[i]], 1);
        perm[pos] = i;
    }
}

// ---------------- fused gate + softmax + pooled ------------------------------
// 1 wave / segment; two 32-lane halves each own one row per iteration
// (float4/lane). Two-level pipeline: perm id prefetched 2 iters ahead,
// x-row load issued 1 iter ahead. No max-subtract (cancels in the ratio).
// Stores sum_e (punned float) into cursor[wid] for k_out's bias scaling.
__global__ __launch_bounds__(256) void k_main(
        const float* __restrict__ x, const int* __restrict__ perm,
        const int* __restrict__ cnt, int* __restrict__ cursor,
        const float* __restrict__ Wg, const float* __restrict__ bg,
        float* __restrict__ pooled, int S) {
    int wid  = (blockIdx.x * blockDim.x + threadIdx.x) >> 6;   // wave = segment
    int lane = threadIdx.x & 63;
    if (wid >= S) return;
    const int n     = cnt[wid];
    const int start = cursor[wid] - n;
    const int half  = lane >> 5;         // which row of the pair
    const int c     = (lane & 31) * 4;   // 4 columns owned by this lane
    const float4 wv = *(const float4*)(Wg + c);
    const float  b0 = bg[0];
    float4 acc = make_float4(0.f, 0.f, 0.f, 0.f);
    float  se  = 0.f;
    const int nt = (n + 1) >> 1;         // row pairs
    // pipeline state: xc = x row for iter t; ridN/vN = row id for iter t+1
    float4 xc = make_float4(0.f, 0.f, 0.f, 0.f);
    int ridN = 0; bool vC = false, vN = false;
    if (nt > 0) {
        int r0 = half;
        vC = (r0 < n);
        int rid0 = perm[start + (vC ? r0 : 0)];
        if (vC) xc = *(const float4*)(x + (size_t)rid0 * D + c);
    }
    if (nt > 1) {
        int r1 = 2 + half;
        vN = (r1 < n);
        ridN = perm[start + (vN ? r1 : 0)];
    }
    for (int t = 0; t < nt; ++t) {
        // issue x load for t+1
        float4 xn = make_float4(0.f, 0.f, 0.f, 0.f);
        if (t + 1 < nt && vN)
            xn = *(const float4*)(x + (size_t)ridN * D + c);
        // issue perm load for t+2
        bool vN2 = false; int ridN2 = 0;
        if (t + 2 < nt) {
            int r2 = 2 * (t + 2) + half;
            vN2 = (r2 < n);
            ridN2 = perm[start + (vN2 ? r2 : 0)];
        }
        // compute on xc (5-step reduce within the 32-lane half)
        float p = xc.x * wv.x + xc.y * wv.y + xc.z * wv.z + xc.w * wv.w;
        p += __shfl_xor(p, 1, 64);
        p += __shfl_xor(p, 2, 64);
        p += __shfl_xor(p, 4, 64);
        p += __shfl_xor(p, 8, 64);
        p += __shfl_xor(p, 16, 64);
        float e = vC ? __expf(p + b0) : 0.f;
        acc.x += e * xc.x; acc.y += e * xc.y;
        acc.z += e * xc.z; acc.w += e * xc.w;
        se += e;
        xc = xn; vC = vN; vN = vN2; ridN = ridN2;
    }
    // combine the two halves
    se    += __shfl_xor(se,    32, 64);
    acc.x += __shfl_xor(acc.x, 32, 64);
    acc.y += __shfl_xor(acc.y, 32, 64);
    acc.z += __shfl_xor(acc.z, 32, 64);
    acc.w += __shfl_xor(acc.w, 32, 64);
    if (half == 0) {
        float inv = 1.f / (se + 1e-10f);
        *(float4*)(pooled + (size_t)wid * D + c) =
            make_float4(acc.x * inv, acc.y * inv, acc.z * inv, acc.w * inv);
        if (lane == 0) ((float*)cursor)[wid] = se;   // segsum for k_out
    }
}

// ---------------- out = pooled @ Wm + (se/(se+1e-10))*bm ---------------------
#define OUT_ROWS 64
__global__ __launch_bounds__(256) void k_out(
        const float* __restrict__ pooled, const float* __restrict__ Wm,
        const float* __restrict__ bm, const float* __restrict__ segsum,
        float* __restrict__ out, int S) {
    __shared__ float Alds[16][64];       // [kk][row] 4 KiB
    __shared__ float Blds[16][128];      // [kk][col] 8 KiB
    const int tx = threadIdx.x & 31;
    const int ty = threadIdx.x >> 5;
    const int r0 = blockIdx.x * OUT_ROWS;
    float acc[8][4] = {{0.f}};
    const int arow = threadIdx.x & 63;
    const int akq  = threadIdx.x >> 6;
    const int brow = threadIdx.x >> 4;
    const int bcol = (threadIdx.x & 15) * 8;

    for (int k0 = 0; k0 < D; k0 += 16) {
        float4 av = make_float4(0.f, 0.f, 0.f, 0.f);
        if (r0 + arow < S)
            av = *(const float4*)(pooled + (size_t)(r0 + arow) * D + k0 + akq * 4);
        Alds[akq * 4 + 0][arow] = av.x;
        Alds[akq * 4 + 1][arow] = av.y;
        Alds[akq * 4 + 2][arow] = av.z;
        Alds[akq * 4 + 3][arow] = av.w;
        *(float4*)(&Blds[brow][bcol])     = *(const float4*)(Wm + (size_t)(k0 + brow) * D + bcol);
        *(float4*)(&Blds[brow][bcol + 4]) = *(const float4*)(Wm + (size_t)(k0 + brow) * D + bcol + 4);
        __syncthreads();
        #pragma unroll
        for (int kk = 0; kk < 16; ++kk) {
            float4 a0 = *(const float4*)(&Alds[kk][ty * 8]);
            float4 a1 = *(const float4*)(&Alds[kk][ty * 8 + 4]);
            float4 b  = *(const float4*)(&Blds[kk][tx * 4]);
            float av8[8] = {a0.x, a0.y, a0.z, a0.w, a1.x, a1.y, a1.z, a1.w};
            #pragma unroll
            for (int i = 0; i < 8; ++i) {
                acc[i][0] += av8[i] * b.x;
                acc[i][1] += av8[i] * b.y;
                acc[i][2] += av8[i] * b.z;
                acc[i][3] += av8[i] * b.w;
            }
        }
        __syncthreads();
    }
    const float4 bv = *(const float4*)(bm + tx * 4);
    #pragma unroll
    for (int i = 0; i < 8; ++i) {
        int r = r0 + ty * 8 + i;
        if (r < S) {
            float ssv = segsum[r];
            float wsc = ssv / (ssv + 1e-10f);
            float4 o;
            o.x = acc[i][0] + wsc * bv.x;
            o.y = acc[i][1] + wsc * bv.y;
            o.z = acc[i][2] + wsc * bv.z;
            o.w = acc[i][3] + wsc * bv.w;
            *(float4*)(out + (size_t)r * D + tx * 4) = o;
        }
    }
}

extern "C" void kernel_launch(void* const* d_in, const int* in_sizes, int n_in,
                              void* d_out, int out_size, void* d_ws, size_t ws_size,
                              hipStream_t stream) {
    const float* x     = (const float*)d_in[0];
    const int*   index = (const int*)  d_in[1];
    const float* Wg    = (const float*)d_in[2];
    const float* bg    = (const float*)d_in[3];
    const float* Wm    = (const float*)d_in[4];
    const float* bm    = (const float*)d_in[5];
    float* out = (float*)d_out;

    const int N_ = in_sizes[0] / D;     // 1,000,000
    const int S_ = out_size / D;        // 50,000

    // workspace: [cnt S][cursor S][bsum 256][perm N][pooled S*D]
    int*   cnt    = (int*)d_ws;
    int*   cursor = cnt + S_;
    int*   bsum   = cursor + S_;
    int*   perm   = bsum + 256;
    float* pooled = (float*)(perm + (size_t)N_);

    const int nb = (S_ + SCAN_CHUNK - 1) / SCAN_CHUNK;    // 25

    hipMemsetAsync(cnt, 0, (size_t)S_ * sizeof(int), stream);

    dim3 blk(256);
    k_hist   <<<dim3((N_ + 255) / 256), blk, 0, stream>>>(index, cnt, N_);
    k_scanA  <<<dim3(nb),               blk, 0, stream>>>(cnt, cursor, bsum, S_);
    k_scanB  <<<dim3(1),                blk, 0, stream>>>(bsum, nb);
    k_scanC  <<<dim3((S_ + 255) / 256), blk, 0, stream>>>(cursor, bsum, S_);
    k_scatter<<<dim3((N_ + 255) / 256), blk, 0, stream>>>(index, cursor, perm, N_);
    k_main   <<<dim3((S_ + 3) / 4),     blk, 0, stream>>>(x, perm, cnt, cursor, Wg, bg, pooled, S_);
    k_out    <<<dim3((S_ + OUT_ROWS - 1) / OUT_ROWS), blk, 0, stream>>>(
                 pooled, Wm, bm, (const float*)cursor, out, S_);
}

// Round 5
// 287.380 us; speedup vs baseline: 7.6072x; 1.0186x over previous
//
#include <hip/hip_runtime.h>

#define D 128

// ---------------- kernel 1: histogram of segment ids -------------------------
__global__ __launch_bounds__(256) void k_hist(
        const int* __restrict__ index, int* __restrict__ cnt, int n) {
    int i = blockIdx.x * blockDim.x + threadIdx.x;
    if (i < n) atomicAdd(&cnt[index[i]], 1);
}

// ---------------- hierarchical exclusive scan: cnt -> cursor -----------------
#define SCAN_CHUNK 2048
__global__ __launch_bounds__(256) void k_scanA(
        const int* __restrict__ cnt, int* __restrict__ cursor,
        int* __restrict__ bsum, int S) {
    __shared__ int tsum[256];
    const int base = blockIdx.x * SCAN_CHUNK;
    int vals[8]; int local = 0;
    #pragma unroll
    for (int j = 0; j < 8; ++j) {
        int i = base + threadIdx.x * 8 + j;
        vals[j] = (i < S) ? cnt[i] : 0;
        local += vals[j];
    }
    tsum[threadIdx.x] = local;
    __syncthreads();
    #pragma unroll
    for (int off = 1; off < 256; off <<= 1) {
        int t = (threadIdx.x >= off) ? tsum[threadIdx.x - off] : 0;
        __syncthreads();
        tsum[threadIdx.x] += t;
        __syncthreads();
    }
    int excl = tsum[threadIdx.x] - local;
    #pragma unroll
    for (int j = 0; j < 8; ++j) {
        int i = base + threadIdx.x * 8 + j;
        if (i < S) cursor[i] = excl;
        excl += vals[j];
    }
    if (threadIdx.x == 255) bsum[blockIdx.x] = tsum[255];
}

__global__ __launch_bounds__(256) void k_scanB(int* __restrict__ bsum, int nb) {
    __shared__ int buf[256];
    int v = (threadIdx.x < nb) ? bsum[threadIdx.x] : 0;
    buf[threadIdx.x] = v;
    __syncthreads();
    #pragma unroll
    for (int off = 1; off < 256; off <<= 1) {
        int t = (threadIdx.x >= off) ? buf[threadIdx.x - off] : 0;
        __syncthreads();
        buf[threadIdx.x] += t;
        __syncthreads();
    }
    if (threadIdx.x < nb) bsum[threadIdx.x] = buf[threadIdx.x] - v;
}

__global__ __launch_bounds__(256) void k_scanC(
        int* __restrict__ cursor, const int* __restrict__ bsum, int S) {
    int i = blockIdx.x * blockDim.x + threadIdx.x;
    if (i < S) cursor[i] += bsum[i / SCAN_CHUNK];
}

// ---------------- scatter row ids into segment-sorted perm -------------------
__global__ __launch_bounds__(256) void k_scatter(
        const int* __restrict__ index, int* __restrict__ cursor,
        int* __restrict__ perm, int n) {
    int i = blockIdx.x * blockDim.x + threadIdx.x;
    if (i < n) {
        int pos = atomicAdd(&cursor[index[i]], 1);
        perm[pos] = i;
    }
}

// ---------------- fused gate + softmax + pooled ------------------------------
// 1 wave / segment. Per 64-row chunk: perm entries loaded coalesced (one per
// lane), row ids then distributed by __shfl (VALU, no load dependency).
// Two 32-lane halves each own one row (float4/lane); depth-2 prefetch ring
// keeps >=4 row gathers in flight per wave. No max-subtract (cancels in the
// ratio). Stores sum_e (punned float) into cursor[wid] for k_out.
__global__ __launch_bounds__(256) void k_main(
        const float* __restrict__ x, const int* __restrict__ perm,
        const int* __restrict__ cnt, int* __restrict__ cursor,
        const float* __restrict__ Wg, const float* __restrict__ bg,
        float* __restrict__ pooled, int S) {
    int wid  = (blockIdx.x * blockDim.x + threadIdx.x) >> 6;   // wave = segment
    int lane = threadIdx.x & 63;
    if (wid >= S) return;
    const int n     = cnt[wid];
    const int start = cursor[wid] - n;
    const int half  = lane >> 5;         // which row of the pair
    const int c     = (lane & 31) * 4;   // 4 columns owned by this lane
    const float4 wv = *(const float4*)(Wg + c);
    const float  b0 = bg[0];
    float4 acc = make_float4(0.f, 0.f, 0.f, 0.f);
    float  se  = 0.f;

    for (int c0 = 0; c0 < n; c0 += 64) {          // 64-row chunks (n>64 is rare)
        const int m = min(64, n - c0);
        int pv = (lane < m) ? perm[start + c0 + lane] : 0;
        const int mt = (m + 1) >> 1;              // row pairs in chunk
        // depth-2 prefetch ring
        float4 q0 = make_float4(0.f, 0.f, 0.f, 0.f);
        float4 q1 = make_float4(0.f, 0.f, 0.f, 0.f);
        bool v0 = false, v1 = false;
        {
            int r = half;                          // t = 0
            v0 = (r < m);
            int rid = __shfl(pv, r & 63, 64);
            if (v0) q0 = *(const float4*)(x + (size_t)rid * D + c);
        }
        if (mt > 1) {
            int r = 2 + half;                      // t = 1
            v1 = (r < m);
            int rid = __shfl(pv, r & 63, 64);
            if (v1) q1 = *(const float4*)(x + (size_t)rid * D + c);
        }
        for (int t = 0; t < mt; ++t) {
            float4 cur = q0; bool vc = v0;
            q0 = q1; v0 = v1;
            v1 = false;
            q1 = make_float4(0.f, 0.f, 0.f, 0.f);
            if (t + 2 < mt) {                      // load for t+2
                int r = (t + 2) * 2 + half;
                v1 = (r < m);
                int rid = __shfl(pv, r & 63, 64);
                if (v1) q1 = *(const float4*)(x + (size_t)rid * D + c);
            }
            float p = cur.x * wv.x + cur.y * wv.y + cur.z * wv.z + cur.w * wv.w;
            p += __shfl_xor(p, 1, 64);
            p += __shfl_xor(p, 2, 64);
            p += __shfl_xor(p, 4, 64);
            p += __shfl_xor(p, 8, 64);
            p += __shfl_xor(p, 16, 64);
            float e = vc ? __expf(p + b0) : 0.f;
            acc.x += e * cur.x; acc.y += e * cur.y;
            acc.z += e * cur.z; acc.w += e * cur.w;
            se += e;
        }
    }
    // combine the two halves
    se    += __shfl_xor(se,    32, 64);
    acc.x += __shfl_xor(acc.x, 32, 64);
    acc.y += __shfl_xor(acc.y, 32, 64);
    acc.z += __shfl_xor(acc.z, 32, 64);
    acc.w += __shfl_xor(acc.w, 32, 64);
    if (half == 0) {
        float inv = 1.f / (se + 1e-10f);
        *(float4*)(pooled + (size_t)wid * D + c) =
            make_float4(acc.x * inv, acc.y * inv, acc.z * inv, acc.w * inv);
        if (lane == 0) ((float*)cursor)[wid] = se;   // segsum for k_out
    }
}

// ---------------- out = pooled @ Wm + (se/(se+1e-10))*bm ---------------------
#define OUT_ROWS 64
__global__ __launch_bounds__(256) void k_out(
        const float* __restrict__ pooled, const float* __restrict__ Wm,
        const float* __restrict__ bm, const float* __restrict__ segsum,
        float* __restrict__ out, int S) {
    __shared__ float Alds[16][64];       // [kk][row] 4 KiB
    __shared__ float Blds[16][128];      // [kk][col] 8 KiB
    const int tx = threadIdx.x & 31;
    const int ty = threadIdx.x >> 5;
    const int r0 = blockIdx.x * OUT_ROWS;
    float acc[8][4] = {{0.f}};
    const int arow = threadIdx.x & 63;
    const int akq  = threadIdx.x >> 6;
    const int brow = threadIdx.x >> 4;
    const int bcol = (threadIdx.x & 15) * 8;

    for (int k0 = 0; k0 < D; k0 += 16) {
        float4 av = make_float4(0.f, 0.f, 0.f, 0.f);
        if (r0 + arow < S)
            av = *(const float4*)(pooled + (size_t)(r0 + arow) * D + k0 + akq * 4);
        Alds[akq * 4 + 0][arow] = av.x;
        Alds[akq * 4 + 1][arow] = av.y;
        Alds[akq * 4 + 2][arow] = av.z;
        Alds[akq * 4 + 3][arow] = av.w;
        *(float4*)(&Blds[brow][bcol])     = *(const float4*)(Wm + (size_t)(k0 + brow) * D + bcol);
        *(float4*)(&Blds[brow][bcol + 4]) = *(const float4*)(Wm + (size_t)(k0 + brow) * D + bcol + 4);
        __syncthreads();
        #pragma unroll
        for (int kk = 0; kk < 16; ++kk) {
            float4 a0 = *(const float4*)(&Alds[kk][ty * 8]);
            float4 a1 = *(const float4*)(&Alds[kk][ty * 8 + 4]);
            float4 b  = *(const float4*)(&Blds[kk][tx * 4]);
            float av8[8] = {a0.x, a0.y, a0.z, a0.w, a1.x, a1.y, a1.z, a1.w};
            #pragma unroll
            for (int i = 0; i < 8; ++i) {
                acc[i][0] += av8[i] * b.x;
                acc[i][1] += av8[i] * b.y;
                acc[i][2] += av8[i] * b.z;
                acc[i][3] += av8[i] * b.w;
            }
        }
        __syncthreads();
    }
    const float4 bv = *(const float4*)(bm + tx * 4);
    #pragma unroll
    for (int i = 0; i < 8; ++i) {
        int r = r0 + ty * 8 + i;
        if (r < S) {
            float ssv = segsum[r];
            float wsc = ssv / (ssv + 1e-10f);
            float4 o;
            o.x = acc[i][0] + wsc * bv.x;
            o.y = acc[i][1] + wsc * bv.y;
            o.z = acc[i][2] + wsc * bv.z;
            o.w = acc[i][3] + wsc * bv.w;
            *(float4*)(out + (size_t)r * D + tx * 4) = o;
        }
    }
}

extern "C" void kernel_launch(void* const* d_in, const int* in_sizes, int n_in,
                              void* d_out, int out_size, void* d_ws, size_t ws_size,
                              hipStream_t stream) {
    const float* x     = (const float*)d_in[0];
    const int*   index = (const int*)  d_in[1];
    const float* Wg    = (const float*)d_in[2];
    const float* bg    = (const float*)d_in[3];
    const float* Wm    = (const float*)d_in[4];
    const float* bm    = (const float*)d_in[5];
    float* out = (float*)d_out;

    const int N_ = in_sizes[0] / D;     // 1,000,000
    const int S_ = out_size / D;        // 50,000

    // workspace: [cnt S][cursor S][bsum 256][perm N][pooled S*D]
    int*   cnt    = (int*)d_ws;
    int*   cursor = cnt + S_;
    int*   bsum   = cursor + S_;
    int*   perm   = bsum + 256;
    float* pooled = (float*)(perm + (size_t)N_);

    const int nb = (S_ + SCAN_CHUNK - 1) / SCAN_CHUNK;    // 25

    hipMemsetAsync(cnt, 0, (size_t)S_ * sizeof(int), stream);

    dim3 blk(256);
    k_hist   <<<dim3((N_ + 255) / 256), blk, 0, stream>>>(index, cnt, N_);
    k_scanA  <<<dim3(nb),               blk, 0, stream>>>(cnt, cursor, bsum, S_);
    k_scanB  <<<dim3(1),                blk, 0, stream>>>(bsum, nb);
    k_scanC  <<<dim3((S_ + 255) / 256), blk, 0, stream>>>(cursor, bsum, S_);
    k_scatter<<<dim3((N_ + 255) / 256), blk, 0, stream>>>(index, cursor, perm, N_);
    k_main   <<<dim3((S_ + 3) / 4),     blk, 0, stream>>>(x, perm, cnt, cursor, Wg, bg, pooled, S_);
    k_out    <<<dim3((S_ + OUT_ROWS - 1) / OUT_ROWS), blk, 0, stream>>>(
                 pooled, Wm, bm, (const float*)cursor, out, S_);
}

// Round 6
// 283.841 us; speedup vs baseline: 7.7021x; 1.0125x over previous
//
#include <hip/hip_runtime.h>

#define D 128

// ---------------- kernel 1: histogram of segment ids -------------------------
__global__ __launch_bounds__(256) void k_hist(
        const int* __restrict__ index, int* __restrict__ cnt, int n) {
    int i = blockIdx.x * blockDim.x + threadIdx.x;
    if (i < n) atomicAdd(&cnt[index[i]], 1);
}

// ---------------- hierarchical exclusive scan: cnt -> cursor -----------------
#define SCAN_CHUNK 2048
__global__ __launch_bounds__(256) void k_scanA(
        const int* __restrict__ cnt, int* __restrict__ cursor,
        int* __restrict__ bsum, int S) {
    __shared__ int tsum[256];
    const int base = blockIdx.x * SCAN_CHUNK;
    int vals[8]; int local = 0;
    #pragma unroll
    for (int j = 0; j < 8; ++j) {
        int i = base + threadIdx.x * 8 + j;
        vals[j] = (i < S) ? cnt[i] : 0;
        local += vals[j];
    }
    tsum[threadIdx.x] = local;
    __syncthreads();
    #pragma unroll
    for (int off = 1; off < 256; off <<= 1) {
        int t = (threadIdx.x >= off) ? tsum[threadIdx.x - off] : 0;
        __syncthreads();
        tsum[threadIdx.x] += t;
        __syncthreads();
    }
    int excl = tsum[threadIdx.x] - local;
    #pragma unroll
    for (int j = 0; j < 8; ++j) {
        int i = base + threadIdx.x * 8 + j;
        if (i < S) cursor[i] = excl;
        excl += vals[j];
    }
    if (threadIdx.x == 255) bsum[blockIdx.x] = tsum[255];
}

__global__ __launch_bounds__(256) void k_scanB(int* __restrict__ bsum, int nb) {
    __shared__ int buf[256];
    int v = (threadIdx.x < nb) ? bsum[threadIdx.x] : 0;
    buf[threadIdx.x] = v;
    __syncthreads();
    #pragma unroll
    for (int off = 1; off < 256; off <<= 1) {
        int t = (threadIdx.x >= off) ? buf[threadIdx.x - off] : 0;
        __syncthreads();
        buf[threadIdx.x] += t;
        __syncthreads();
    }
    if (threadIdx.x < nb) bsum[threadIdx.x] = buf[threadIdx.x] - v;
}

__global__ __launch_bounds__(256) void k_scanC(
        int* __restrict__ cursor, const int* __restrict__ bsum, int S) {
    int i = blockIdx.x * blockDim.x + threadIdx.x;
    if (i < S) cursor[i] += bsum[i / SCAN_CHUNK];
}

// ---------------- scatter row ids into segment-sorted perm -------------------
__global__ __launch_bounds__(256) void k_scatter(
        const int* __restrict__ index, int* __restrict__ cursor,
        int* __restrict__ perm, int n) {
    int i = blockIdx.x * blockDim.x + threadIdx.x;
    if (i < n) {
        int pos = atomicAdd(&cursor[index[i]], 1);
        perm[pos] = i;
    }
}

// ---------------- fused gate + softmax + pooled ------------------------------
// 1 wave / segment. perm entries for a 64-row chunk loaded coalesced (one per
// lane), row ids distributed via __shfl. Two 32-lane halves each own one row
// (float4/lane); DEPTH-4 named-register prefetch ring keeps ~8 row gathers
// (4 KB) in flight per wave. No max-subtract (cancels in the ratio).
// Stores sum_e (punned float) into cursor[wid] for k_out.
__global__ __launch_bounds__(256) void k_main(
        const float* __restrict__ x, const int* __restrict__ perm,
        const int* __restrict__ cnt, int* __restrict__ cursor,
        const float* __restrict__ Wg, const float* __restrict__ bg,
        float* __restrict__ pooled, int S) {
    int wid  = (blockIdx.x * blockDim.x + threadIdx.x) >> 6;   // wave = segment
    int lane = threadIdx.x & 63;
    if (wid >= S) return;
    const int n     = cnt[wid];
    const int start = cursor[wid] - n;
    const int half  = lane >> 5;         // which row of the pair
    const int c     = (lane & 31) * 4;   // 4 columns owned by this lane
    const float4 wv = *(const float4*)(Wg + c);
    const float  b0 = bg[0];
    float4 acc = make_float4(0.f, 0.f, 0.f, 0.f);
    float  se  = 0.f;

    for (int c0 = 0; c0 < n; c0 += 64) {          // one chunk for n<=64 (typ.)
        const int m = min(64, n - c0);
        int pv = (lane < m) ? perm[start + c0 + lane] : 0;
        const int mt = (m + 1) >> 1;              // row pairs in chunk

        float4 q0, q1, q2, q3;
        bool   v0, v1, v2, v3;
#define LOADT(Q, V, T)                                                        \
        {                                                                     \
            int r_ = 2 * (T) + half;                                          \
            (V) = (r_ < m);                                                   \
            int rid_ = __shfl(pv, r_ & 63, 64);                               \
            (Q) = make_float4(0.f, 0.f, 0.f, 0.f);                            \
            if (V) (Q) = *(const float4*)(x + (size_t)rid_ * D + c);          \
        }
        LOADT(q0, v0, 0)
        LOADT(q1, v1, 1)
        LOADT(q2, v2, 2)
        LOADT(q3, v3, 3)
        for (int t = 0; t < mt; ++t) {
            float4 cur = q0; bool vc = v0;
            q0 = q1; v0 = v1;
            q1 = q2; v1 = v2;
            q2 = q3; v2 = v3;
            LOADT(q3, v3, t + 4)
            float p = cur.x * wv.x + cur.y * wv.y + cur.z * wv.z + cur.w * wv.w;
            p += __shfl_xor(p, 1, 64);
            p += __shfl_xor(p, 2, 64);
            p += __shfl_xor(p, 4, 64);
            p += __shfl_xor(p, 8, 64);
            p += __shfl_xor(p, 16, 64);
            float e = vc ? __expf(p + b0) : 0.f;
            acc.x += e * cur.x; acc.y += e * cur.y;
            acc.z += e * cur.z; acc.w += e * cur.w;
            se += e;
        }
#undef LOADT
    }
    // combine the two halves
    se    += __shfl_xor(se,    32, 64);
    acc.x += __shfl_xor(acc.x, 32, 64);
    acc.y += __shfl_xor(acc.y, 32, 64);
    acc.z += __shfl_xor(acc.z, 32, 64);
    acc.w += __shfl_xor(acc.w, 32, 64);
    if (half == 0) {
        float inv = 1.f / (se + 1e-10f);
        *(float4*)(pooled + (size_t)wid * D + c) =
            make_float4(acc.x * inv, acc.y * inv, acc.z * inv, acc.w * inv);
        if (lane == 0) ((float*)cursor)[wid] = se;   // segsum for k_out
    }
}

// ---------------- out = pooled @ Wm + (se/(se+1e-10))*bm ---------------------
#define OUT_ROWS 64
__global__ __launch_bounds__(256) void k_out(
        const float* __restrict__ pooled, const float* __restrict__ Wm,
        const float* __restrict__ bm, const float* __restrict__ segsum,
        float* __restrict__ out, int S) {
    __shared__ float Alds[16][64];       // [kk][row] 4 KiB
    __shared__ float Blds[16][128];      // [kk][col] 8 KiB
    const int tx = threadIdx.x & 31;
    const int ty = threadIdx.x >> 5;
    const int r0 = blockIdx.x * OUT_ROWS;
    float acc[8][4] = {{0.f}};
    const int arow = threadIdx.x & 63;
    const int akq  = threadIdx.x >> 6;
    const int brow = threadIdx.x >> 4;
    const int bcol = (threadIdx.x & 15) * 8;

    for (int k0 = 0; k0 < D; k0 += 16) {
        float4 av = make_float4(0.f, 0.f, 0.f, 0.f);
        if (r0 + arow < S)
            av = *(const float4*)(pooled + (size_t)(r0 + arow) * D + k0 + akq * 4);
        Alds[akq * 4 + 0][arow] = av.x;
        Alds[akq * 4 + 1][arow] = av.y;
        Alds[akq * 4 + 2][arow] = av.z;
        Alds[akq * 4 + 3][arow] = av.w;
        *(float4*)(&Blds[brow][bcol])     = *(const float4*)(Wm + (size_t)(k0 + brow) * D + bcol);
        *(float4*)(&Blds[brow][bcol + 4]) = *(const float4*)(Wm + (size_t)(k0 + brow) * D + bcol + 4);
        __syncthreads();
        #pragma unroll
        for (int kk = 0; kk < 16; ++kk) {
            float4 a0 = *(const float4*)(&Alds[kk][ty * 8]);
            float4 a1 = *(const float4*)(&Alds[kk][ty * 8 + 4]);
            float4 b  = *(const float4*)(&Blds[kk][tx * 4]);
            float av8[8] = {a0.x, a0.y, a0.z, a0.w, a1.x, a1.y, a1.z, a1.w};
            #pragma unroll
            for (int i = 0; i < 8; ++i) {
                acc[i][0] += av8[i] * b.x;
                acc[i][1] += av8[i] * b.y;
                acc[i][2] += av8[i] * b.z;
                acc[i][3] += av8[i] * b.w;
            }
        }
        __syncthreads();
    }
    const float4 bv = *(const float4*)(bm + tx * 4);
    #pragma unroll
    for (int i = 0; i < 8; ++i) {
        int r = r0 + ty * 8 + i;
        if (r < S) {
            float ssv = segsum[r];
            float wsc = ssv / (ssv + 1e-10f);
            float4 o;
            o.x = acc[i][0] + wsc * bv.x;
            o.y = acc[i][1] + wsc * bv.y;
            o.z = acc[i][2] + wsc * bv.z;
            o.w = acc[i][3] + wsc * bv.w;
            *(float4*)(out + (size_t)r * D + tx * 4) = o;
        }
    }
}

extern "C" void kernel_launch(void* const* d_in, const int* in_sizes, int n_in,
                              void* d_out, int out_size, void* d_ws, size_t ws_size,
                              hipStream_t stream) {
    const float* x     = (const float*)d_in[0];
    const int*   index = (const int*)  d_in[1];
    const float* Wg    = (const float*)d_in[2];
    const float* bg    = (const float*)d_in[3];
    const float* Wm    = (const float*)d_in[4];
    const float* bm    = (const float*)d_in[5];
    float* out = (float*)d_out;

    const int N_ = in_sizes[0] / D;     // 1,000,000
    const int S_ = out_size / D;        // 50,000

    // workspace: [cnt S][cursor S][bsum 256][perm N][pooled S*D]
    int*   cnt    = (int*)d_ws;
    int*   cursor = cnt + S_;
    int*   bsum   = cursor + S_;
    int*   perm   = bsum + 256;
    float* pooled = (float*)(perm + (size_t)N_);

    const int nb = (S_ + SCAN_CHUNK - 1) / SCAN_CHUNK;    // 25

    hipMemsetAsync(cnt, 0, (size_t)S_ * sizeof(int), stream);

    dim3 blk(256);
    k_hist   <<<dim3((N_ + 255) / 256), blk, 0, stream>>>(index, cnt, N_);
    k_scanA  <<<dim3(nb),               blk, 0, stream>>>(cnt, cursor, bsum, S_);
    k_scanB  <<<dim3(1),                blk, 0, stream>>>(bsum, nb);
    k_scanC  <<<dim3((S_ + 255) / 256), blk, 0, stream>>>(cursor, bsum, S_);
    k_scatter<<<dim3((N_ + 255) / 256), blk, 0, stream>>>(index, cursor, perm, N_);
    k_main   <<<dim3((S_ + 3) / 4),     blk, 0, stream>>>(x, perm, cnt, cursor, Wg, bg, pooled, S_);
    k_out    <<<dim3((S_ + OUT_ROWS - 1) / OUT_ROWS), blk, 0, stream>>>(
                 pooled, Wm, bm, (const float*)cursor, out, S_);
}